// Round 8
// baseline (791.757 us; speedup 1.0000x reference)
//
#include <hip/hip_runtime.h>
#include <math.h>

// UpTransition: up-GEMM -> sparse conv(32) -> BN+ELU -> cat(skip max) ->
// 2x [sparse conv(64) -> BN+ELU] -> ELU(h + xcat)
//
// R6 post-mortem: k_red (pos-table, 27 branch-dependent gathers/output,
// 640 blocks) was latency-bound: 95.9us each, VALUBusy 2%, HBM 5%, occ 17%.
// Replaced with per-output entry lists: ent[o][0..deg[o]) built by atomic
// scatter; k_red2 does deg[o] independent branch-free gathers, grid 2500.

__device__ __forceinline__ float elu(float v) { return v > 0.f ? v : expm1f(v); }

__device__ __forceinline__ float4 f4add(float4 a, float4 b) {
  return make_float4(a.x + b.x, a.y + b.y, a.z + b.z, a.w + b.w);
}

// ---------------- init: deg = 0, stats = 0, zero pad rows ----------------
__global__ void __launch_bounds__(256) k_init(int* __restrict__ deg, float* __restrict__ stats,
                                              float* __restrict__ upz, float* __restrict__ xcz,
                                              int NF) {
  int i = blockIdx.x * blockDim.x + threadIdx.x;
  for (int j = i; j < NF; j += gridDim.x * blockDim.x) deg[j] = 0;
  if (i < 384) stats[i] = 0.f;
  if (i < 64) { upz[i] = 0.f; xcz[i] = 0.f; }
}

// ---------------- meta: per-k counts (binary search on NF padding) + bases --
__global__ void k_meta(const int* __restrict__ in_idx, int mmax, int NF,
                       int* __restrict__ cnt, int* __restrict__ base) {
  __shared__ int sc[27];
  int k = threadIdx.x;
  if (k < 27) {
    int lo = 0, hi = mmax;
    while (lo < hi) {
      int mid = (lo + hi) >> 1;
      if (in_idx[(size_t)k * mmax + mid] >= NF) hi = mid; else lo = mid + 1;
    }
    sc[k] = lo;
    cnt[k] = lo;
  }
  __syncthreads();
  if (threadIdx.x == 0) {
    int acc = 0;
    for (int j = 0; j < 27; ++j) { base[j] = acc; acc += (sc[j] + 127) & ~127; }
    base[27] = acc;
  }
}

// ---------------- scatter2: ent[o][slot] = base[k] + m ----------------
__global__ void __launch_bounds__(256) k_scatter2(const int* __restrict__ out_idx, int mmax,
                                                  const int* __restrict__ cnt, const int* __restrict__ base,
                                                  int* __restrict__ deg, int* __restrict__ ent) {
  int k = blockIdx.y;
  int m = blockIdx.x * blockDim.x + threadIdx.x;
  if (m >= cnt[k]) return;
  int o = out_idx[(size_t)k * mmax + m];
  int s = atomicAdd(deg + o, 1);
  ent[(size_t)o * 32 + s] = base[k] + m;  // max 27 entries < 32
}

// ---------------- up: up[4n+j] = x[n] @ w_up[j] ----------------
template <int RU>
__global__ void __launch_bounds__(256) k_up(const float* __restrict__ x, const float* __restrict__ w_up,
                                            float* __restrict__ up, int NC) {
  const int lane = threadIdx.x & 63;
  const int j = threadIdx.x >> 6;  // wave = which of the 4 transpose-conv taps
  float wreg[64];
#pragma unroll
  for (int ci = 0; ci < 64; ++ci) wreg[ci] = w_up[(size_t)(j * 64 + ci) * 64 + lane];
  const int n0 = blockIdx.x * RU;
#pragma unroll
  for (int r = 0; r < RU; ++r) {
    int n = n0 + r;
    if (n >= NC) break;
    const float* xr = x + (size_t)n * 64;  // wave-uniform -> scalar loads
    float a0 = 0.f, a1 = 0.f, a2 = 0.f, a3 = 0.f;
#pragma unroll
    for (int ci = 0; ci < 64; ci += 4) {
      a0 = fmaf(xr[ci + 0], wreg[ci + 0], a0);
      a1 = fmaf(xr[ci + 1], wreg[ci + 1], a1);
      a2 = fmaf(xr[ci + 2], wreg[ci + 2], a2);
      a3 = fmaf(xr[ci + 3], wreg[ci + 3], a3);
    }
    up[(size_t)(n * 4 + j) * 64 + lane] = (a0 + a1) + (a2 + a3);
  }
}

// ---------------- pair-list LDS-tiled GEMM ----------------
// Block: 64 pairs x COUT cols, K=64. A^T staged in LDS (stride 68), W in LDS.
// Thread (mi=tid>>4, ci=tid&15) computes rows 4mi..4mi+3, cols CW*ci..
template <int COUT>
__global__ void __launch_bounds__(256) k_gemm2(const float* __restrict__ x,   // (NF+1) x 64, row NF zero
                                               const float* __restrict__ w,   // [27][64][COUT]
                                               const int* __restrict__ in_idx, int mmax, int NF,
                                               const int* __restrict__ cnt, const int* __restrict__ base,
                                               float* __restrict__ Cbuf) {
  constexpr int CW = COUT / 16;  // cols per thread: 4 (COUT=64) or 2 (COUT=32)
  constexpr int STA = 68;        // A^T row stride: 16B-aligned b128, conflict-free
  __shared__ float At[64 * STA];  // A^T[kk][m]
  __shared__ float Ws[64 * COUT]; // W[kk][c]
  __shared__ int sidx[64];

  const int k = blockIdx.y;
  const int ck = cnt[k];
  const int m0 = blockIdx.x * 64;
  if (m0 >= ck) return;
  const int tid = threadIdx.x;

  if (tid < 64) {
    int m = m0 + tid;
    sidx[tid] = (m < ck) ? in_idx[(size_t)k * mmax + m] : NF;  // pad -> zero row
  }
  {  // stage W panel (contiguous copy)
    const float4* wsrc = (const float4*)(w + (size_t)k * 64 * COUT);
    float4* wdst = (float4*)Ws;
#pragma unroll
    for (int p = 0; p < 64 * COUT / 4 / 256; ++p) wdst[tid + p * 256] = wsrc[tid + p * 256];
  }
  __syncthreads();
  {  // stage A^T: 4 passes; row=tid&15(+16/pass), 16B chunk=tid>>4
    const int r0 = tid & 15;
    const int cb = tid >> 4;  // floats 4cb..4cb+3
#pragma unroll
    for (int p = 0; p < 4; ++p) {
      int row = r0 + p * 16;
      float4 v = *(const float4*)(x + (size_t)sidx[row] * 64 + cb * 4);
      At[(cb * 4 + 0) * STA + row] = v.x;
      At[(cb * 4 + 1) * STA + row] = v.y;
      At[(cb * 4 + 2) * STA + row] = v.z;
      At[(cb * 4 + 3) * STA + row] = v.w;
    }
  }
  __syncthreads();

  const int mi = tid >> 4;  // 0..15
  const int ci = tid & 15;  // 0..15
  float acc[4][CW];
#pragma unroll
  for (int i = 0; i < 4; ++i)
#pragma unroll
    for (int j = 0; j < CW; ++j) acc[i][j] = 0.f;

#pragma unroll 4
  for (int kk = 0; kk < 64; ++kk) {
    float4 a = *(const float4*)(At + kk * STA + mi * 4);
    const float* brow = Ws + kk * COUT + ci * CW;
    float b[CW];
#pragma unroll
    for (int j = 0; j < CW; ++j) b[j] = brow[j];
    float av[4] = {a.x, a.y, a.z, a.w};
#pragma unroll
    for (int i = 0; i < 4; ++i)
#pragma unroll
      for (int j = 0; j < CW; ++j) acc[i][j] = fmaf(av[i], b[j], acc[i][j]);
  }

  const int bk = base[k];
#pragma unroll
  for (int i = 0; i < 4; ++i) {
    float* dst = Cbuf + (size_t)(bk + m0 + mi * 4 + i) * COUT + ci * CW;
#pragma unroll
    for (int j = 0; j < CW; ++j) dst[j] = acc[i][j];
  }
}

// ---------------- reduce partials via entry lists + BN stats ----------------
template <int COUT>
__global__ void __launch_bounds__(256) k_red2(const float* __restrict__ Cbuf, const int* __restrict__ deg,
                                              const int* __restrict__ ent, float* __restrict__ y,
                                              float* __restrict__ s1, float* __restrict__ s2, int NF) {
  constexpr int C4 = COUT / 4;
  const int c4 = threadIdx.x & (C4 - 1);
  const int rl = threadIdx.x / C4;
  constexpr int rpb = 256 / C4;
  float4 p1 = make_float4(0, 0, 0, 0), p2 = make_float4(0, 0, 0, 0);
  for (int o = blockIdx.x * rpb + rl; o < NF; o += gridDim.x * rpb) {
    const int d = deg[o];
    const int* el = ent + (size_t)o * 32;
    float4 acc = make_float4(0, 0, 0, 0);
    for (int j = 0; j < d; ++j) {  // branch-free: all gathers independent
      int p = el[j];
      float4 v = *(const float4*)(Cbuf + (size_t)p * COUT + c4 * 4);
      acc = f4add(acc, v);
    }
    *(float4*)(y + (size_t)o * COUT + c4 * 4) = acc;
    p1 = f4add(p1, acc);
    p2 = f4add(p2, make_float4(acc.x * acc.x, acc.y * acc.y, acc.z * acc.z, acc.w * acc.w));
  }
  __shared__ float4 sh[256];
  sh[threadIdx.x] = p1;
  __syncthreads();
  if (rl == 0) {
    float4 t = make_float4(0, 0, 0, 0);
    for (int r = 0; r < rpb; ++r) t = f4add(t, sh[r * C4 + c4]);
    atomicAdd(s1 + c4 * 4 + 0, t.x); atomicAdd(s1 + c4 * 4 + 1, t.y);
    atomicAdd(s1 + c4 * 4 + 2, t.z); atomicAdd(s1 + c4 * 4 + 3, t.w);
  }
  __syncthreads();
  sh[threadIdx.x] = p2;
  __syncthreads();
  if (rl == 0) {
    float4 t = make_float4(0, 0, 0, 0);
    for (int r = 0; r < rpb; ++r) t = f4add(t, sh[r * C4 + c4]);
    atomicAdd(s2 + c4 * 4 + 0, t.x); atomicAdd(s2 + c4 * 4 + 1, t.y);
    atomicAdd(s2 + c4 * 4 + 2, t.z); atomicAdd(s2 + c4 * 4 + 3, t.w);
  }
}

// ---------------- xcat = [ELU(BN(y1)), max_t(skip)] ----------------
__global__ void __launch_bounds__(256) k_xcat(const float* __restrict__ y1, const float* __restrict__ skip,
                                              const float* __restrict__ gamma, const float* __restrict__ beta,
                                              const float* __restrict__ s1, const float* __restrict__ s2,
                                              float* __restrict__ xcat, int NF) {
  int t = blockIdx.x * blockDim.x + threadIdx.x;
  if (t >= NF * 32) return;
  int c = t & 31, o = t >> 5;
  float invn = 1.f / (float)NF;
  float m = s1[c] * invn;
  float var = s2[c] * invn - m * m;
  float sc = rsqrtf(var + 1e-5f) * gamma[c];
  float v = (y1[(size_t)o * 32 + c] - m) * sc + beta[c];
  xcat[(size_t)o * 64 + c] = elu(v);
  float a = skip[((size_t)o * 2) * 32 + c];
  float b = skip[((size_t)o * 2 + 1) * 32 + c];
  xcat[(size_t)o * 64 + 32 + c] = fmaxf(a, b);
}

// ---------------- h = ELU(BN(y)) ----------------
__global__ void __launch_bounds__(256) k_norm(const float* __restrict__ y, const float* __restrict__ gamma,
                                              const float* __restrict__ beta, const float* __restrict__ s1,
                                              const float* __restrict__ s2, float* __restrict__ h, int NF) {
  int t = blockIdx.x * blockDim.x + threadIdx.x;
  if (t >= NF * 64) return;
  int c = t & 63;
  float invn = 1.f / (float)NF;
  float m = s1[c] * invn;
  float var = s2[c] * invn - m * m;
  float sc = rsqrtf(var + 1e-5f) * gamma[c];
  h[t] = elu((y[t] - m) * sc + beta[c]);
}

// ---------------- out = ELU(ELU(BN(y3)) + xcat) ----------------
__global__ void __launch_bounds__(256) k_final(const float* __restrict__ y, const float* __restrict__ gamma,
                                               const float* __restrict__ beta, const float* __restrict__ s1,
                                               const float* __restrict__ s2, const float* __restrict__ xcat,
                                               float* __restrict__ out, int NF) {
  int t = blockIdx.x * blockDim.x + threadIdx.x;
  if (t >= NF * 64) return;
  int c = t & 63;
  float invn = 1.f / (float)NF;
  float m = s1[c] * invn;
  float var = s2[c] * invn - m * m;
  float sc = rsqrtf(var + 1e-5f) * gamma[c];
  float v = elu((y[t] - m) * sc + beta[c]);
  out[t] = elu(v + xcat[t]);
}

extern "C" void kernel_launch(void* const* d_in, const int* in_sizes, int n_in,
                              void* d_out, int out_size, void* d_ws, size_t ws_size,
                              hipStream_t stream) {
  const float* x_feats  = (const float*)d_in[0];
  const float* skip     = (const float*)d_in[1];
  const float* w_up     = (const float*)d_in[2];
  const float* w_upconv = (const float*)d_in[3];
  const float* bn1_g    = (const float*)d_in[4];
  const float* bn1_b    = (const float*)d_in[5];
  const float* convs_w  = (const float*)d_in[6];
  const float* convs_g  = (const float*)d_in[7];
  const float* convs_b  = (const float*)d_in[8];
  const int*   in_idx   = (const int*)d_in[9];
  const int*   out_idx  = (const int*)d_in[10];

  const int NC = in_sizes[0] / 64;
  const int NF = 4 * NC;
  const int mmax = in_sizes[9] / 27;

  char* ws = (char*)d_ws;
  size_t off = 0;
  auto alloc = [&](size_t bytes) -> void* {
    void* p = ws + off;
    off += (bytes + 255) & ~(size_t)255;
    return p;
  };
  int*   deg   = (int*)alloc((size_t)NF * 4);
  int*   ent   = (int*)alloc((size_t)NF * 32 * 4);
  int*   cnt   = (int*)alloc(32 * 4);
  int*   basep = (int*)alloc(32 * 4);
  float* stats = (float*)alloc(384 * 4);  // 3 stages x (sum, sumsq) x 64
  float* up    = (float*)alloc(((size_t)NF + 1) * 64 * 4);
  float* xcat  = (float*)alloc(((size_t)NF + 1) * 64 * 4);
  float* y     = (float*)alloc((size_t)NF * 64 * 4);  // reused y1/y2/y3
  float* Cb    = (float*)(ws + off);                  // remainder: partial rows
  float* h     = up;  // up is dead after the first k_gemm2; pad row stays zero

  k_init<<<160, 256, 0, stream>>>(deg, stats, up + (size_t)NF * 64,
                                  xcat + (size_t)NF * 64, NF);
  k_meta<<<1, 64, 0, stream>>>(in_idx, mmax, NF, cnt, basep);
  dim3 gs((mmax + 255) / 256, 27);
  k_scatter2<<<gs, 256, 0, stream>>>(out_idx, mmax, cnt, basep, deg, ent);
  k_up<16><<<(NC + 15) / 16, 256, 0, stream>>>(x_feats, w_up, up, NC);

  dim3 gg((mmax + 63) / 64, 27);  // 64-pair tiles; blocks past cnt[k] exit
  // upconv (COUT=32) -> BN1 stats
  k_gemm2<32><<<gg, 256, 0, stream>>>(up, w_upconv, in_idx, mmax, NF, cnt, basep, Cb);
  k_red2<32><<<(NF + 31) / 32, 256, 0, stream>>>(Cb, deg, ent, y, stats + 0, stats + 64, NF);
  k_xcat<<<(NF * 32 + 255) / 256, 256, 0, stream>>>(y, skip, bn1_g, bn1_b,
                                                    stats + 0, stats + 64, xcat, NF);
  // conv1
  k_gemm2<64><<<gg, 256, 0, stream>>>(xcat, convs_w, in_idx, mmax, NF, cnt, basep, Cb);
  k_red2<64><<<(NF + 15) / 16, 256, 0, stream>>>(Cb, deg, ent, y, stats + 128, stats + 192, NF);
  k_norm<<<(NF * 64 + 255) / 256, 256, 0, stream>>>(y, convs_g, convs_b,
                                                    stats + 128, stats + 192, h, NF);
  // conv2
  k_gemm2<64><<<gg, 256, 0, stream>>>(h, convs_w + 27 * 64 * 64, in_idx, mmax, NF, cnt, basep, Cb);
  k_red2<64><<<(NF + 15) / 16, 256, 0, stream>>>(Cb, deg, ent, y, stats + 256, stats + 320, NF);
  k_final<<<(NF * 64 + 255) / 256, 256, 0, stream>>>(y, convs_g + 64, convs_b + 64,
                                                     stats + 256, stats + 320, xcat,
                                                     (float*)d_out, NF);
}

// Round 9
// 781.081 us; speedup vs baseline: 1.0137x; 1.0137x over previous
//
#include <hip/hip_runtime.h>
#include <math.h>

// UpTransition: up-GEMM -> sparse conv(32) -> BN+ELU -> cat(skip max) ->
// 2x [sparse conv(64) -> BN+ELU] -> ELU(h + xcat)
//
// R8 post-mortem: k_red2's runtime-bounded gather loop serialized loads
// (MLP~1.5): 250us, VALUBusy 0.85%, HBM 2%, occ 48% (all waves stalled).
// k_red3 restores static MLP: entry list -> 7 named int4 regs (7 indep
// loads), then 27 statically-unrolled predicated gathers (invalid -> slot-0
// row, wave-local L1 hit). All 34 loads independent -> compiler pipelines.

__device__ __forceinline__ float elu(float v) { return v > 0.f ? v : expm1f(v); }

__device__ __forceinline__ float4 f4add(float4 a, float4 b) {
  return make_float4(a.x + b.x, a.y + b.y, a.z + b.z, a.w + b.w);
}

// ---------------- init: deg = 0, stats = 0, zero pad rows ----------------
__global__ void __launch_bounds__(256) k_init(int* __restrict__ deg, float* __restrict__ stats,
                                              float* __restrict__ upz, float* __restrict__ xcz,
                                              int NF) {
  int i = blockIdx.x * blockDim.x + threadIdx.x;
  for (int j = i; j < NF; j += gridDim.x * blockDim.x) deg[j] = 0;
  if (i < 384) stats[i] = 0.f;
  if (i < 64) { upz[i] = 0.f; xcz[i] = 0.f; }
}

// ---------------- meta: per-k counts (binary search on NF padding) + bases --
__global__ void k_meta(const int* __restrict__ in_idx, int mmax, int NF,
                       int* __restrict__ cnt, int* __restrict__ base) {
  __shared__ int sc[27];
  int k = threadIdx.x;
  if (k < 27) {
    int lo = 0, hi = mmax;
    while (lo < hi) {
      int mid = (lo + hi) >> 1;
      if (in_idx[(size_t)k * mmax + mid] >= NF) hi = mid; else lo = mid + 1;
    }
    sc[k] = lo;
    cnt[k] = lo;
  }
  __syncthreads();
  if (threadIdx.x == 0) {
    int acc = 0;
    for (int j = 0; j < 27; ++j) { base[j] = acc; acc += (sc[j] + 127) & ~127; }
    base[27] = acc;
  }
}

// ---------------- scatter2: ent[o][slot] = base[k] + m ----------------
__global__ void __launch_bounds__(256) k_scatter2(const int* __restrict__ out_idx, int mmax,
                                                  const int* __restrict__ cnt, const int* __restrict__ base,
                                                  int* __restrict__ deg, int* __restrict__ ent) {
  int k = blockIdx.y;
  int m = blockIdx.x * blockDim.x + threadIdx.x;
  if (m >= cnt[k]) return;
  int o = out_idx[(size_t)k * mmax + m];
  int s = atomicAdd(deg + o, 1);
  ent[(size_t)o * 32 + s] = base[k] + m;  // max 27 entries < 32
}

// ---------------- up: up[4n+j] = x[n] @ w_up[j] ----------------
template <int RU>
__global__ void __launch_bounds__(256) k_up(const float* __restrict__ x, const float* __restrict__ w_up,
                                            float* __restrict__ up, int NC) {
  const int lane = threadIdx.x & 63;
  const int j = threadIdx.x >> 6;  // wave = which of the 4 transpose-conv taps
  float wreg[64];
#pragma unroll
  for (int ci = 0; ci < 64; ++ci) wreg[ci] = w_up[(size_t)(j * 64 + ci) * 64 + lane];
  const int n0 = blockIdx.x * RU;
#pragma unroll
  for (int r = 0; r < RU; ++r) {
    int n = n0 + r;
    if (n >= NC) break;
    const float* xr = x + (size_t)n * 64;  // wave-uniform -> scalar loads
    float a0 = 0.f, a1 = 0.f, a2 = 0.f, a3 = 0.f;
#pragma unroll
    for (int ci = 0; ci < 64; ci += 4) {
      a0 = fmaf(xr[ci + 0], wreg[ci + 0], a0);
      a1 = fmaf(xr[ci + 1], wreg[ci + 1], a1);
      a2 = fmaf(xr[ci + 2], wreg[ci + 2], a2);
      a3 = fmaf(xr[ci + 3], wreg[ci + 3], a3);
    }
    up[(size_t)(n * 4 + j) * 64 + lane] = (a0 + a1) + (a2 + a3);
  }
}

// ---------------- pair-list LDS-tiled GEMM ----------------
// Block: 64 pairs x COUT cols, K=64. A^T staged in LDS (stride 68), W in LDS.
// Thread (mi=tid>>4, ci=tid&15) computes rows 4mi..4mi+3, cols CW*ci..
template <int COUT>
__global__ void __launch_bounds__(256) k_gemm2(const float* __restrict__ x,   // (NF+1) x 64, row NF zero
                                               const float* __restrict__ w,   // [27][64][COUT]
                                               const int* __restrict__ in_idx, int mmax, int NF,
                                               const int* __restrict__ cnt, const int* __restrict__ base,
                                               float* __restrict__ Cbuf) {
  constexpr int CW = COUT / 16;  // cols per thread: 4 (COUT=64) or 2 (COUT=32)
  constexpr int STA = 68;        // A^T row stride: 16B-aligned b128, conflict-free
  __shared__ float At[64 * STA];  // A^T[kk][m]
  __shared__ float Ws[64 * COUT]; // W[kk][c]
  __shared__ int sidx[64];

  const int k = blockIdx.y;
  const int ck = cnt[k];
  const int m0 = blockIdx.x * 64;
  if (m0 >= ck) return;
  const int tid = threadIdx.x;

  if (tid < 64) {
    int m = m0 + tid;
    sidx[tid] = (m < ck) ? in_idx[(size_t)k * mmax + m] : NF;  // pad -> zero row
  }
  {  // stage W panel (contiguous copy)
    const float4* wsrc = (const float4*)(w + (size_t)k * 64 * COUT);
    float4* wdst = (float4*)Ws;
#pragma unroll
    for (int p = 0; p < 64 * COUT / 4 / 256; ++p) wdst[tid + p * 256] = wsrc[tid + p * 256];
  }
  __syncthreads();
  {  // stage A^T: 4 passes; row=tid&15(+16/pass), 16B chunk=tid>>4
    const int r0 = tid & 15;
    const int cb = tid >> 4;  // floats 4cb..4cb+3
#pragma unroll
    for (int p = 0; p < 4; ++p) {
      int row = r0 + p * 16;
      float4 v = *(const float4*)(x + (size_t)sidx[row] * 64 + cb * 4);
      At[(cb * 4 + 0) * STA + row] = v.x;
      At[(cb * 4 + 1) * STA + row] = v.y;
      At[(cb * 4 + 2) * STA + row] = v.z;
      At[(cb * 4 + 3) * STA + row] = v.w;
    }
  }
  __syncthreads();

  const int mi = tid >> 4;  // 0..15
  const int ci = tid & 15;  // 0..15
  float acc[4][CW];
#pragma unroll
  for (int i = 0; i < 4; ++i)
#pragma unroll
    for (int j = 0; j < CW; ++j) acc[i][j] = 0.f;

#pragma unroll 4
  for (int kk = 0; kk < 64; ++kk) {
    float4 a = *(const float4*)(At + kk * STA + mi * 4);
    const float* brow = Ws + kk * COUT + ci * CW;
    float b[CW];
#pragma unroll
    for (int j = 0; j < CW; ++j) b[j] = brow[j];
    float av[4] = {a.x, a.y, a.z, a.w};
#pragma unroll
    for (int i = 0; i < 4; ++i)
#pragma unroll
      for (int j = 0; j < CW; ++j) acc[i][j] = fmaf(av[i], b[j], acc[i][j]);
  }

  const int bk = base[k];
#pragma unroll
  for (int i = 0; i < 4; ++i) {
    float* dst = Cbuf + (size_t)(bk + m0 + mi * 4 + i) * COUT + ci * CW;
#pragma unroll
    for (int j = 0; j < CW; ++j) dst[j] = acc[i][j];
  }
}

// ---------------- reduce partials: static-unrolled predicated gathers ------
// Slot 0 is always valid (self tap => deg>=1); j>=d lanes re-gather slot-0's
// row (wave-local cache hit) and discard via predicated add.
template <int COUT>
__global__ void __launch_bounds__(256) k_red3(const float* __restrict__ Cbuf, const int* __restrict__ deg,
                                              const int* __restrict__ ent, float* __restrict__ y,
                                              float* __restrict__ s1, float* __restrict__ s2, int NF) {
  constexpr int C4 = COUT / 4;
  const int c4 = threadIdx.x & (C4 - 1);
  const int rl = threadIdx.x / C4;
  constexpr int rpb = 256 / C4;
  float4 p1 = make_float4(0, 0, 0, 0), p2 = make_float4(0, 0, 0, 0);
  for (int o = blockIdx.x * rpb + rl; o < NF; o += gridDim.x * rpb) {
    const int d = deg[o];
    const int4* el4 = (const int4*)(ent + (size_t)o * 32);
    int4 e0 = el4[0], e1 = el4[1], e2 = el4[2], e3 = el4[3];
    int4 e4 = el4[4], e5 = el4[5], e6 = el4[6];
    const int ps = e0.x;  // always valid
    float4 acc0 = make_float4(0, 0, 0, 0), acc1 = make_float4(0, 0, 0, 0);
#define GATHER(J, PJ, A)                                                     \
    {                                                                        \
      int pj = ((J) < d) ? (PJ) : ps;                                        \
      float4 v = *(const float4*)(Cbuf + (size_t)pj * COUT + c4 * 4);        \
      if ((J) < d) A = f4add(A, v);                                          \
    }
    GATHER(0, e0.x, acc0)  GATHER(1, e0.y, acc1)  GATHER(2, e0.z, acc0)
    GATHER(3, e0.w, acc1)  GATHER(4, e1.x, acc0)  GATHER(5, e1.y, acc1)
    GATHER(6, e1.z, acc0)  GATHER(7, e1.w, acc1)  GATHER(8, e2.x, acc0)
    GATHER(9, e2.y, acc1)  GATHER(10, e2.z, acc0) GATHER(11, e2.w, acc1)
    GATHER(12, e3.x, acc0) GATHER(13, e3.y, acc1) GATHER(14, e3.z, acc0)
    GATHER(15, e3.w, acc1) GATHER(16, e4.x, acc0) GATHER(17, e4.y, acc1)
    GATHER(18, e4.z, acc0) GATHER(19, e4.w, acc1) GATHER(20, e5.x, acc0)
    GATHER(21, e5.y, acc1) GATHER(22, e5.z, acc0) GATHER(23, e5.w, acc1)
    GATHER(24, e6.x, acc0) GATHER(25, e6.y, acc1) GATHER(26, e6.z, acc0)
#undef GATHER
    float4 acc = f4add(acc0, acc1);
    *(float4*)(y + (size_t)o * COUT + c4 * 4) = acc;
    p1 = f4add(p1, acc);
    p2 = f4add(p2, make_float4(acc.x * acc.x, acc.y * acc.y, acc.z * acc.z, acc.w * acc.w));
  }
  __shared__ float4 sh[256];
  sh[threadIdx.x] = p1;
  __syncthreads();
  if (rl == 0) {
    float4 t = make_float4(0, 0, 0, 0);
    for (int r = 0; r < rpb; ++r) t = f4add(t, sh[r * C4 + c4]);
    atomicAdd(s1 + c4 * 4 + 0, t.x); atomicAdd(s1 + c4 * 4 + 1, t.y);
    atomicAdd(s1 + c4 * 4 + 2, t.z); atomicAdd(s1 + c4 * 4 + 3, t.w);
  }
  __syncthreads();
  sh[threadIdx.x] = p2;
  __syncthreads();
  if (rl == 0) {
    float4 t = make_float4(0, 0, 0, 0);
    for (int r = 0; r < rpb; ++r) t = f4add(t, sh[r * C4 + c4]);
    atomicAdd(s2 + c4 * 4 + 0, t.x); atomicAdd(s2 + c4 * 4 + 1, t.y);
    atomicAdd(s2 + c4 * 4 + 2, t.z); atomicAdd(s2 + c4 * 4 + 3, t.w);
  }
}

// ---------------- xcat = [ELU(BN(y1)), max_t(skip)] ----------------
__global__ void __launch_bounds__(256) k_xcat(const float* __restrict__ y1, const float* __restrict__ skip,
                                              const float* __restrict__ gamma, const float* __restrict__ beta,
                                              const float* __restrict__ s1, const float* __restrict__ s2,
                                              float* __restrict__ xcat, int NF) {
  int t = blockIdx.x * blockDim.x + threadIdx.x;
  if (t >= NF * 32) return;
  int c = t & 31, o = t >> 5;
  float invn = 1.f / (float)NF;
  float m = s1[c] * invn;
  float var = s2[c] * invn - m * m;
  float sc = rsqrtf(var + 1e-5f) * gamma[c];
  float v = (y1[(size_t)o * 32 + c] - m) * sc + beta[c];
  xcat[(size_t)o * 64 + c] = elu(v);
  float a = skip[((size_t)o * 2) * 32 + c];
  float b = skip[((size_t)o * 2 + 1) * 32 + c];
  xcat[(size_t)o * 64 + 32 + c] = fmaxf(a, b);
}

// ---------------- h = ELU(BN(y)) ----------------
__global__ void __launch_bounds__(256) k_norm(const float* __restrict__ y, const float* __restrict__ gamma,
                                              const float* __restrict__ beta, const float* __restrict__ s1,
                                              const float* __restrict__ s2, float* __restrict__ h, int NF) {
  int t = blockIdx.x * blockDim.x + threadIdx.x;
  if (t >= NF * 64) return;
  int c = t & 63;
  float invn = 1.f / (float)NF;
  float m = s1[c] * invn;
  float var = s2[c] * invn - m * m;
  float sc = rsqrtf(var + 1e-5f) * gamma[c];
  h[t] = elu((y[t] - m) * sc + beta[c]);
}

// ---------------- out = ELU(ELU(BN(y3)) + xcat) ----------------
__global__ void __launch_bounds__(256) k_final(const float* __restrict__ y, const float* __restrict__ gamma,
                                               const float* __restrict__ beta, const float* __restrict__ s1,
                                               const float* __restrict__ s2, const float* __restrict__ xcat,
                                               float* __restrict__ out, int NF) {
  int t = blockIdx.x * blockDim.x + threadIdx.x;
  if (t >= NF * 64) return;
  int c = t & 63;
  float invn = 1.f / (float)NF;
  float m = s1[c] * invn;
  float var = s2[c] * invn - m * m;
  float sc = rsqrtf(var + 1e-5f) * gamma[c];
  float v = elu((y[t] - m) * sc + beta[c]);
  out[t] = elu(v + xcat[t]);
}

extern "C" void kernel_launch(void* const* d_in, const int* in_sizes, int n_in,
                              void* d_out, int out_size, void* d_ws, size_t ws_size,
                              hipStream_t stream) {
  const float* x_feats  = (const float*)d_in[0];
  const float* skip     = (const float*)d_in[1];
  const float* w_up     = (const float*)d_in[2];
  const float* w_upconv = (const float*)d_in[3];
  const float* bn1_g    = (const float*)d_in[4];
  const float* bn1_b    = (const float*)d_in[5];
  const float* convs_w  = (const float*)d_in[6];
  const float* convs_g  = (const float*)d_in[7];
  const float* convs_b  = (const float*)d_in[8];
  const int*   in_idx   = (const int*)d_in[9];
  const int*   out_idx  = (const int*)d_in[10];

  const int NC = in_sizes[0] / 64;
  const int NF = 4 * NC;
  const int mmax = in_sizes[9] / 27;

  char* ws = (char*)d_ws;
  size_t off = 0;
  auto alloc = [&](size_t bytes) -> void* {
    void* p = ws + off;
    off += (bytes + 255) & ~(size_t)255;
    return p;
  };
  int*   deg   = (int*)alloc((size_t)NF * 4);
  int*   ent   = (int*)alloc((size_t)NF * 32 * 4);
  int*   cnt   = (int*)alloc(32 * 4);
  int*   basep = (int*)alloc(32 * 4);
  float* stats = (float*)alloc(384 * 4);  // 3 stages x (sum, sumsq) x 64
  float* up    = (float*)alloc(((size_t)NF + 1) * 64 * 4);
  float* xcat  = (float*)alloc(((size_t)NF + 1) * 64 * 4);
  float* y     = (float*)alloc((size_t)NF * 64 * 4);  // reused y1/y2/y3
  float* Cb    = (float*)(ws + off);                  // remainder: partial rows
  float* h     = up;  // up is dead after the first k_gemm2; pad row stays zero

  k_init<<<160, 256, 0, stream>>>(deg, stats, up + (size_t)NF * 64,
                                  xcat + (size_t)NF * 64, NF);
  k_meta<<<1, 64, 0, stream>>>(in_idx, mmax, NF, cnt, basep);
  dim3 gs((mmax + 255) / 256, 27);
  k_scatter2<<<gs, 256, 0, stream>>>(out_idx, mmax, cnt, basep, deg, ent);
  k_up<16><<<(NC + 15) / 16, 256, 0, stream>>>(x_feats, w_up, up, NC);

  dim3 gg((mmax + 63) / 64, 27);  // 64-pair tiles; blocks past cnt[k] exit
  // upconv (COUT=32) -> BN1 stats
  k_gemm2<32><<<gg, 256, 0, stream>>>(up, w_upconv, in_idx, mmax, NF, cnt, basep, Cb);
  k_red3<32><<<(NF + 31) / 32, 256, 0, stream>>>(Cb, deg, ent, y, stats + 0, stats + 64, NF);
  k_xcat<<<(NF * 32 + 255) / 256, 256, 0, stream>>>(y, skip, bn1_g, bn1_b,
                                                    stats + 0, stats + 64, xcat, NF);
  // conv1
  k_gemm2<64><<<gg, 256, 0, stream>>>(xcat, convs_w, in_idx, mmax, NF, cnt, basep, Cb);
  k_red3<64><<<(NF + 15) / 16, 256, 0, stream>>>(Cb, deg, ent, y, stats + 128, stats + 192, NF);
  k_norm<<<(NF * 64 + 255) / 256, 256, 0, stream>>>(y, convs_g, convs_b,
                                                    stats + 128, stats + 192, h, NF);
  // conv2
  k_gemm2<64><<<gg, 256, 0, stream>>>(h, convs_w + 27 * 64 * 64, in_idx, mmax, NF, cnt, basep, Cb);
  k_red3<64><<<(NF + 15) / 16, 256, 0, stream>>>(Cb, deg, ent, y, stats + 256, stats + 320, NF);
  k_final<<<(NF * 64 + 255) / 256, 256, 0, stream>>>(y, convs_g + 64, convs_b + 64,
                                                     stats + 256, stats + 320, xcat,
                                                     (float*)d_out, NF);
}